// Round 2
// baseline (317.437 us; speedup 1.0000x reference)
//
#include <hip/hip_runtime.h>
#include <math.h>

// RadialProfileLoss — windowed-Gaussian radial histogram formulation.
// sigma = bin_width/2  =>  W[p][b] = exp(-2*(u_p-(b+0.5))^2), u = r/bw.
// Tail beyond +-3.5 bins < 2.3e-11 relative -> 8-bin window is exact to fp32.
// Per-thread column walk: |du/dy| <= 0.504 < 1 so the window base moves by at
// most 1 per row; window lives in statically-indexed registers (no scratch),
// G=4 images/block share the per-pixel weight recurrence (2 exp2 per pixel).

#define NBINS 64
#define WIN   8
#define G     4          // images per block
#define NIMG  384        // 32*12
#define HDIM  256
#define WDIM  256
#define BANDS 8
#define BANDROWS 32      // HDIM / BANDS

#define DEN_BANDS 128    // den kernel: 2-row bands so it spreads across CUs
#define DEN_ROWS  2

#define LOG2E 1.4426950408889634f
#define EXP_M4 0.018315638888734179f   // e^-4

__device__ __forceinline__ float fexp2(float x) {
#if __has_builtin(__builtin_amdgcn_exp2f)
  return __builtin_amdgcn_exp2f(x);
#else
  return exp2f(x);
#endif
}

// ---------------------------------------------------------------------------
// Main profile kernel: prof[g][0][b] += sum_p pred[g][p]*W[p][b] (same targ).
// thread = one column x; walks BANDROWS rows of its band.
// ---------------------------------------------------------------------------
__global__ __launch_bounds__(256) void radial_prof_kernel(
    const float* __restrict__ pred,
    const float* __restrict__ targ,
    float* __restrict__ prof)          // [NIMG][2][NBINS]
{
  const int x     = threadIdx.x;               // column 0..255
  const int band  = blockIdx.x & (BANDS - 1);  // 0..7
  const int chunk = blockIdx.x >> 3;           // 0..95
  const int g0    = chunk * G;

  __shared__ float hist[G][2][NBINS];
  for (int i = threadIdx.x; i < G * 2 * NBINS; i += 256) ((float*)hist)[i] = 0.f;
  __syncthreads();

  const float dx     = (float)x - 127.5f;
  const float dx2    = dx * dx;
  const int   y0     = band * BANDROWS;
  const float inv_bw = 64.0f / 127.0f;

  float acc[G][2][WIN];
  #pragma unroll
  for (int g = 0; g < G; ++g)
    #pragma unroll
    for (int i = 0; i < 2; ++i)
      #pragma unroll
      for (int s = 0; s < WIN; ++s) acc[g][i][s] = 0.f;

  int k0;
  {
    const float dy = (float)y0 - 127.5f;
    k0 = (int)floorf(sqrtf(dx2 + dy * dy) * inv_bw) - 3;
  }

  const size_t istr = (size_t)HDIM * WDIM;
  const float* pp = pred + (size_t)g0 * istr + (size_t)y0 * WDIM + x;
  const float* tp = targ + (size_t)g0 * istr + (size_t)y0 * WDIM + x;

  for (int yi = 0; yi < BANDROWS; ++yi) {
    const float dy = (float)(y0 + yi) - 127.5f;
    const float r  = sqrtf(dx2 + dy * dy);
    const float u  = r * inv_bw;
    const float fl = floorf(u);
    const int   k  = (int)fl - 3;

    if (k != k0) {
      if (k == k0 + 1) {                 // window slides down: flush slot 0
        if ((unsigned)k0 < NBINS) {
          #pragma unroll
          for (int g = 0; g < G; ++g) {
            atomicAdd(&hist[g][0][k0], acc[g][0][0]);
            atomicAdd(&hist[g][1][k0], acc[g][1][0]);
          }
        }
        #pragma unroll
        for (int g = 0; g < G; ++g)
          #pragma unroll
          for (int i = 0; i < 2; ++i) {
            #pragma unroll
            for (int s = 0; s < WIN - 1; ++s) acc[g][i][s] = acc[g][i][s + 1];
            acc[g][i][WIN - 1] = 0.f;
          }
      } else if (k == k0 - 1) {          // window slides up: flush slot 7
        const int bh = k0 + WIN - 1;
        if ((unsigned)bh < NBINS) {
          #pragma unroll
          for (int g = 0; g < G; ++g) {
            atomicAdd(&hist[g][0][bh], acc[g][0][WIN - 1]);
            atomicAdd(&hist[g][1][bh], acc[g][1][WIN - 1]);
          }
        }
        #pragma unroll
        for (int g = 0; g < G; ++g)
          #pragma unroll
          for (int i = 0; i < 2; ++i) {
            #pragma unroll
            for (int s = WIN - 1; s > 0; --s) acc[g][i][s] = acc[g][i][s - 1];
            acc[g][i][0] = 0.f;
          }
      } else {                           // safety: big jump — flush everything
        #pragma unroll
        for (int s = 0; s < WIN; ++s) {
          const int b = k0 + s;
          if ((unsigned)b < NBINS) {
            #pragma unroll
            for (int g = 0; g < G; ++g) {
              atomicAdd(&hist[g][0][b], acc[g][0][s]);
              atomicAdd(&hist[g][1][b], acc[g][1][s]);
            }
          }
        }
        #pragma unroll
        for (int g = 0; g < G; ++g)
          #pragma unroll
          for (int i = 0; i < 2; ++i)
            #pragma unroll
            for (int s = 0; s < WIN; ++s) acc[g][i][s] = 0.f;
      }
      k0 = k;
    }

    if (k0 < NBINS) {   // skip pixels whose whole window is past bin 63
      // t0 = frac(u)+2.5 in [2.5,3.5); slot s weight = exp(-2 (t0-s)^2)
      const float t0 = (u - fl) + 2.5f;
      float w = fexp2(-(2.0f * LOG2E) * t0 * t0);
      float m = fexp2((4.0f * t0 - 2.0f) * LOG2E);
      float xp[G], xt[G];
      #pragma unroll
      for (int g = 0; g < G; ++g) {
        xp[g] = pp[(size_t)g * istr];
        xt[g] = tp[(size_t)g * istr];
      }
      #pragma unroll
      for (int s = 0; s < WIN; ++s) {
        #pragma unroll
        for (int g = 0; g < G; ++g) {
          acc[g][0][s] = fmaf(w, xp[g], acc[g][0][s]);
          acc[g][1][s] = fmaf(w, xt[g], acc[g][1][s]);
        }
        w *= m;
        m *= EXP_M4;
      }
    }
    pp += WDIM; tp += WDIM;
  }

  // final flush of remaining window
  #pragma unroll
  for (int s = 0; s < WIN; ++s) {
    const int b = k0 + s;
    if ((unsigned)b < NBINS) {
      #pragma unroll
      for (int g = 0; g < G; ++g) {
        atomicAdd(&hist[g][0][b], acc[g][0][s]);
        atomicAdd(&hist[g][1][b], acc[g][1][s]);
      }
    }
  }
  __syncthreads();

  for (int i = threadIdx.x; i < G * 2 * NBINS; i += 256)
    atomicAdd(&prof[(size_t)g0 * 2 * NBINS + i], ((float*)hist)[i]);
}

// ---------------------------------------------------------------------------
// den[b] = sum_p W[p][b]  (data-independent; 2-row bands -> 128 blocks so it
// doesn't serialize the pipeline on 8 CUs)
// ---------------------------------------------------------------------------
__global__ __launch_bounds__(256) void den_kernel(float* __restrict__ den)
{
  const int x    = threadIdx.x;
  const int band = blockIdx.x;   // 0..DEN_BANDS-1
  __shared__ float hist[NBINS];
  if (threadIdx.x < NBINS) hist[threadIdx.x] = 0.f;
  __syncthreads();

  const float dx     = (float)x - 127.5f;
  const float dx2    = dx * dx;
  const int   y0     = band * DEN_ROWS;
  const float inv_bw = 64.0f / 127.0f;

  float acc[WIN];
  #pragma unroll
  for (int s = 0; s < WIN; ++s) acc[s] = 0.f;

  int k0;
  {
    const float dy = (float)y0 - 127.5f;
    k0 = (int)floorf(sqrtf(dx2 + dy * dy) * inv_bw) - 3;
  }

  for (int yi = 0; yi < DEN_ROWS; ++yi) {
    const float dy = (float)(y0 + yi) - 127.5f;
    const float r  = sqrtf(dx2 + dy * dy);
    const float u  = r * inv_bw;
    const float fl = floorf(u);
    const int   k  = (int)fl - 3;

    if (k != k0) {
      if (k == k0 + 1) {
        if ((unsigned)k0 < NBINS) atomicAdd(&hist[k0], acc[0]);
        #pragma unroll
        for (int s = 0; s < WIN - 1; ++s) acc[s] = acc[s + 1];
        acc[WIN - 1] = 0.f;
      } else if (k == k0 - 1) {
        const int bh = k0 + WIN - 1;
        if ((unsigned)bh < NBINS) atomicAdd(&hist[bh], acc[WIN - 1]);
        #pragma unroll
        for (int s = WIN - 1; s > 0; --s) acc[s] = acc[s - 1];
        acc[0] = 0.f;
      } else {
        #pragma unroll
        for (int s = 0; s < WIN; ++s) {
          const int b = k0 + s;
          if ((unsigned)b < NBINS) atomicAdd(&hist[b], acc[s]);
          acc[s] = 0.f;
        }
      }
      k0 = k;
    }

    if (k0 < NBINS) {
      const float t0 = (u - fl) + 2.5f;
      float w = fexp2(-(2.0f * LOG2E) * t0 * t0);
      float m = fexp2((4.0f * t0 - 2.0f) * LOG2E);
      #pragma unroll
      for (int s = 0; s < WIN; ++s) {
        acc[s] += w;
        w *= m;
        m *= EXP_M4;
      }
    }
  }

  #pragma unroll
  for (int s = 0; s < WIN; ++s) {
    const int b = k0 + s;
    if ((unsigned)b < NBINS) atomicAdd(&hist[b], acc[s]);
  }
  __syncthreads();
  if (threadIdx.x < NBINS) atomicAdd(&den[threadIdx.x], hist[threadIdx.x]);
}

// ---------------------------------------------------------------------------
// Epilogue: per-image weighted R^2 ratio, mean over 384 images -> scalar.
// w_b = centers_b / mean(centers): the normalization cancels in sse/ssy, so
// only the shape (b+0.5) matters (constant factors cancel too, kept anyway).
// ---------------------------------------------------------------------------
__global__ __launch_bounds__(NIMG) void loss_kernel(
    const float* __restrict__ prof,
    const float* __restrict__ den,
    float* __restrict__ out)
{
  __shared__ float dsh[NBINS];
  __shared__ float red[NIMG];
  const int tid = threadIdx.x;
  if (tid < NBINS) dsh[tid] = 1.0f / fmaxf(den[tid], 1e-8f);
  __syncthreads();

  const float bw = 127.0f / 64.0f;
  const float* base = prof + (size_t)tid * (2 * NBINS);

  float tsum = 0.f;
  for (int b = 0; b < NBINS; ++b) tsum += base[NBINS + b] * dsh[b];
  const float ybar = tsum * (1.0f / NBINS);

  float sse = 0.f, ssy = 0.f;
  for (int b = 0; b < NBINS; ++b) {
    const float wb = ((float)b + 0.5f) * bw * (1.0f / 63.5f);
    const float P  = base[b] * dsh[b];
    const float T  = base[NBINS + b] * dsh[b];
    const float d1 = P - T;
    const float d2 = T - ybar;
    sse = fmaf(wb * d1, d1, sse);
    ssy = fmaf(wb * d2, d2, ssy);
  }
  red[tid] = sse / fmaxf(ssy, 1e-8f);
  __syncthreads();

  for (int s = 256; s > 0; s >>= 1) {
    if (tid < s && tid + s < NIMG) red[tid] += red[tid + s];
    __syncthreads();
  }
  if (tid == 0) out[0] = red[0] * (1.0f / NIMG);
}

// ---------------------------------------------------------------------------
extern "C" void kernel_launch(void* const* d_in, const int* in_sizes, int n_in,
                              void* d_out, int out_size, void* d_ws, size_t ws_size,
                              hipStream_t stream) {
  const float* pred = (const float*)d_in[0];
  const float* targ = (const float*)d_in[1];

  float* prof = (float*)d_ws;                       // NIMG*2*NBINS floats
  float* den  = prof + (size_t)NIMG * 2 * NBINS;    // NBINS floats

  hipMemsetAsync(d_ws, 0, ((size_t)NIMG * 2 * NBINS + NBINS) * sizeof(float), stream);

  den_kernel<<<DEN_BANDS, 256, 0, stream>>>(den);
  radial_prof_kernel<<<(NIMG / G) * BANDS, 256, 0, stream>>>(pred, targ, prof);
  loss_kernel<<<1, NIMG, 0, stream>>>(prof, den, (float*)d_out);
}